// Round 5
// baseline (239.323 us; speedup 1.0000x reference)
//
#include <hip/hip_runtime.h>

// ---------------------------------------------------------------------------
// Algebraic collapse + fp16 MFMA (rounds 1-4) + round-5:
//   - skip folded into G:  out = (G+I) @ x + g   (k6 never reads fp32 x)
//   - no atomics / no memset: k0 writes per-tile sum partials (k2a reduces),
//     k5b writes per-ct gvec partials (k6 reduces 5 terms into LDS)
//   - k3b fused with softmax-over-heads (writes P directly)
// ---------------------------------------------------------------------------

constexpr int kB = 4;
constexpr int kC = 256;
constexpr int kHW = 16384;
constexpr int kHeads = 64;
constexpr int kNG = 32;
constexpr int kCPG = 8;
constexpr int kCP1 = 257;
constexpr int kPS = 260;          // padded row stride (floats) for S / M
constexpr float kEPS = 1e-5f;
constexpr int kNSplit = 32;       // syrk K-splits

typedef __attribute__((ext_vector_type(8))) _Float16 f16x8;
typedef __attribute__((ext_vector_type(4))) _Float16 f16x4;
typedef __attribute__((ext_vector_type(4))) float f32x4;

union V8 { f16x8 v; uint4 u; _Float16 h[8]; };

// workspace layout (float-unit offsets)
constexpr size_t oXT    = 0;                                    // fp16 xT [b][n][c]
constexpr size_t oXH    = oXT + (size_t)kB * kHW * kC / 2;      // fp16 xH [b][c][n]
constexpr size_t oSpart = oXH + (size_t)kB * kHW * kC / 2;      // 3*B*kNSplit*128*128
constexpr size_t oS     = oSpart + (size_t)3 * kB * kNSplit * 128 * 128;
constexpr size_t oSumsP = oS + (size_t)kB * kCP1 * kPS;         // B x 256(nt) x 256(c)
constexpr size_t oSums  = oSumsP + (size_t)kB * 256 * kC;       // B x 256 reduced
constexpr size_t oGvP   = oSums + (size_t)kB * kC;              // B x 256 x 8 (5 used)
constexpr size_t oSc    = oGvP + (size_t)kB * kC * 8;
constexpr size_t oTc    = oSc + (size_t)kB * kC;
constexpr size_t oP     = oTc + (size_t)kB * kC;                // B x 64 x 16 softmax
// overlays (lifetime-disjoint):
constexpr size_t oAq    = oSpart;                               // B x 256 x 257 (after k1r)
constexpr size_t oM     = oXH;                                  // B x 256 x 260 (after k1)
constexpr size_t oGmH   = oXH + (size_t)kB * kC * kPS;          // fp16 B x 256 x 256

// ---------------------------------------------------------------------------
// K0: tiled transpose x -> xT (fp16) + xH (fp16 [b][c][n]) + sum partials.
// grid (HW/64, C/64, B), 256 thr.
// ---------------------------------------------------------------------------
__global__ __launch_bounds__(256) void k0_tr(const float* __restrict__ x,
                                             _Float16* __restrict__ xT,
                                             _Float16* __restrict__ xH,
                                             float* __restrict__ sumsP) {
  const int nt = blockIdx.x, ct = blockIdx.y, b = blockIdx.z;
  __shared__ float T[64][65];
  __shared__ float psum[64][4];
  const float* xb = x + ((size_t)b * kC + ct * 64) * kHW + nt * 64;
  _Float16* xhb = xH + ((size_t)b * kC + ct * 64) * kHW + nt * 64;
  const int tid = threadIdx.x;

#pragma unroll
  for (int rep = 0; rep < 4; ++rep) {
    const int r = rep * 16 + (tid >> 4);          // c-local
    const int c4 = (tid & 15) * 4;                // n-local
    float4 v = *(const float4*)(xb + (size_t)r * kHW + c4);
    T[r][c4 + 0] = v.x; T[r][c4 + 1] = v.y; T[r][c4 + 2] = v.z; T[r][c4 + 3] = v.w;
    f16x4 hv = {(_Float16)v.x, (_Float16)v.y, (_Float16)v.z, (_Float16)v.w};
    *(f16x4*)(xhb + (size_t)r * kHW + c4) = hv;
  }
  __syncthreads();
  {
    const int q = tid >> 6, r = tid & 63;
    float s = 0.f;
#pragma unroll
    for (int i = 0; i < 16; ++i) s += T[r][q * 16 + i];
    psum[r][q] = s;
  }
  __syncthreads();
  if (tid < 64) {
    float s = psum[tid][0] + psum[tid][1] + psum[tid][2] + psum[tid][3];
    sumsP[((size_t)b * 256 + nt) * kC + ct * 64 + tid] = s;   // coalesced, no atomics
  }
  const int nl = tid >> 2, cgrp = tid & 3;
  V8 lo, hi;
#pragma unroll
  for (int i = 0; i < 8; ++i)  lo.h[i] = (_Float16)T[cgrp * 16 + i][nl];
#pragma unroll
  for (int i = 0; i < 8; ++i)  hi.h[i] = (_Float16)T[cgrp * 16 + 8 + i][nl];
  _Float16* dst = xT + ((size_t)b * kHW + nt * 64 + nl) * kC + ct * 64 + cgrp * 16;
  *(uint4*)dst = lo.u;
  *(uint4*)(dst + 8) = hi.u;
}

// ---------------------------------------------------------------------------
// K1: MFMA syrk reading xH. Tiles (0,0),(0,1),(1,1) of 128x128; 32 K-splits.
// grid (3*32, B), 256 thr. LDS swizzle g^(r&7).
// ---------------------------------------------------------------------------
__global__ __launch_bounds__(256) void k1_syrk(const _Float16* __restrict__ xH,
                                               float* __restrict__ Spart) {
  const int tt = blockIdx.x >> 5;   // /kNSplit
  const int sp = blockIdx.x & 31;
  const int b = blockIdx.y;
  const int ti = (tt == 2) ? 1 : 0;
  const int tj = (tt == 0) ? 0 : 1;
  const bool diag = (ti == tj);
  const _Float16* xb = xH + (size_t)b * kC * kHW;
  const int n0 = sp * (kHW / kNSplit);   // 512 per split

  __shared__ __align__(16) _Float16 XI[128 * 64];
  __shared__ __align__(16) _Float16 XJ[128 * 64];

  const int tid = threadIdx.x;
  const int wave = tid >> 6, lane = tid & 63;
  const int wi = wave >> 1, wj = wave & 1;
  const int lrow = lane & 15, lgq = lane >> 4;

  f32x4 acc[16];
#pragma unroll
  for (int i = 0; i < 16; ++i) acc[i] = (f32x4){0.f, 0.f, 0.f, 0.f};

  for (int ch = 0; ch < kHW / kNSplit / 64; ++ch) {
    const int nb = n0 + ch * 64;
#pragma unroll
    for (int rep = 0; rep < 4; ++rep) {
      const int gi = tid + rep * 256;
      const int r = gi >> 3, g = gi & 7;
      const size_t boff = (size_t)r * 128 + (((unsigned)(g ^ (r & 7))) << 4);
      uint4 va = *(const uint4*)(xb + (size_t)(ti * 128 + r) * kHW + nb + g * 8);
      *(uint4*)((char*)XI + boff) = va;
      if (!diag) {
        uint4 vb = *(const uint4*)(xb + (size_t)(tj * 128 + r) * kHW + nb + g * 8);
        *(uint4*)((char*)XJ + boff) = vb;
      }
    }
    __syncthreads();
    const _Float16* XB = diag ? XI : XJ;
#pragma unroll
    for (int sub = 0; sub < 2; ++sub) {
      const int gq = sub * 4 + lgq;
      f16x8 afr[4], bfr[4];
#pragma unroll
      for (int ia = 0; ia < 4; ++ia) {
        const int r = wi * 64 + ia * 16 + lrow;
        afr[ia] = *(const f16x8*)((const char*)XI + (size_t)r * 128 + (((unsigned)(gq ^ (r & 7))) << 4));
      }
#pragma unroll
      for (int jb = 0; jb < 4; ++jb) {
        const int r = wj * 64 + jb * 16 + lrow;
        bfr[jb] = *(const f16x8*)((const char*)XB + (size_t)r * 128 + (((unsigned)(gq ^ (r & 7))) << 4));
      }
#pragma unroll
      for (int ia = 0; ia < 4; ++ia)
#pragma unroll
        for (int jb = 0; jb < 4; ++jb)
          acc[ia * 4 + jb] = __builtin_amdgcn_mfma_f32_16x16x32_f16(afr[ia], bfr[jb], acc[ia * 4 + jb], 0, 0, 0);
    }
    __syncthreads();
  }
  float* P = Spart + (((size_t)tt * kB + b) * kNSplit + sp) * 16384;
#pragma unroll
  for (int ia = 0; ia < 4; ++ia)
#pragma unroll
    for (int jb = 0; jb < 4; ++jb)
#pragma unroll
      for (int reg = 0; reg < 4; ++reg) {
        const int i = wi * 64 + ia * 16 + lgq * 4 + reg;
        const int j = wj * 64 + jb * 16 + lrow;
        P[(size_t)i * 128 + j] = acc[ia * 4 + jb][reg];
      }
}

// ---------------------------------------------------------------------------
// K1r: reduce split partials -> full symmetric padded S (stride kPS).
// grid (3*B*16), 256 thr.
// ---------------------------------------------------------------------------
__global__ __launch_bounds__(256) void k1r_reduce(const float* __restrict__ Spart,
                                                  float* __restrict__ S) {
  const int blk = blockIdx.x;
  const int tile12 = blk >> 4;
  const int part = blk & 15;
  const int tt = tile12 >> 2, b = tile12 & 3;
  const int rti = (tt == 2) ? 1 : 0;
  const int rtj = (tt == 0) ? 0 : 1;
  const int e0 = part * 1024 + threadIdx.x * 4;
  float4 s = {0.f, 0.f, 0.f, 0.f};
  const float* base = Spart + ((size_t)tt * kB + b) * kNSplit * 16384 + e0;
  for (int sp = 0; sp < kNSplit; ++sp) {
    float4 v = *(const float4*)(base + (size_t)sp * 16384);
    s.x += v.x; s.y += v.y; s.z += v.z; s.w += v.w;
  }
  const int i = e0 >> 7, j = e0 & 127;
  float* Sb = S + (size_t)b * kCP1 * kPS;
  float* dst = Sb + (size_t)(rti * 128 + i) * kPS + rtj * 128 + j;
  dst[0] = s.x; dst[1] = s.y; dst[2] = s.z; dst[3] = s.w;
  if (tt == 1) {  // mirror into lower triangle
    Sb[(size_t)(128 + j + 0) * kPS + i] = s.x;
    Sb[(size_t)(128 + j + 1) * kPS + i] = s.y;
    Sb[(size_t)(128 + j + 2) * kPS + i] = s.z;
    Sb[(size_t)(128 + j + 3) * kPS + i] = s.w;
  }
}

// ---------------------------------------------------------------------------
// K2a: reduce sum partials + GN stats -> affine (s_c, t_c) + exact sums.
// grid (B), 256 thr.
// ---------------------------------------------------------------------------
__global__ __launch_bounds__(256) void k2a_stats(const float* __restrict__ S,
                                                 const float* __restrict__ sumsP,
                                                 const float* __restrict__ gw,
                                                 const float* __restrict__ gb,
                                                 float* __restrict__ sArr,
                                                 float* __restrict__ tArr,
                                                 float* __restrict__ sums) {
  const int b = blockIdx.x;
  const float* Sb = S + (size_t)b * kCP1 * kPS;
  __shared__ float sx[kC], sdg[kC], meanv[kNG], invv[kNG];
  const int c = threadIdx.x;
  float accs = 0.f;
  for (int nt = 0; nt < 256; ++nt) accs += sumsP[((size_t)b * 256 + nt) * kC + c];
  sums[b * kC + c] = accs;
  sx[c]  = accs;
  sdg[c] = Sb[(size_t)c * kPS + c];
  __syncthreads();
  if (c < kNG) {
    float sum = 0.f, ssq = 0.f;
    for (int k = 0; k < kCPG; ++k) { sum += sx[c * kCPG + k]; ssq += sdg[c * kCPG + k]; }
    const float n = (float)(kCPG * kHW);
    const float mean = sum / n;
    const float var = (ssq - n * mean * mean) / (n - 1.0f);  // ddof=1
    meanv[c] = mean;
    invv[c] = rsqrtf(var + kEPS);
  }
  __syncthreads();
  const int g = c / kCPG;
  const float s = gw[c] * invv[g];
  sArr[b * kC + c] = s;
  tArr[b * kC + c] = gb[c] - meanv[g] * s;
}

// ---------------------------------------------------------------------------
// K3a: Aq[b,m,cp] = sum_c Wq'[m,c] * Gram'[c,cp], Gram' folded INLINE from
// raw S. grid (5 cp-tiles, 4 m-tiles, B), 256 thr.
// ---------------------------------------------------------------------------
__global__ __launch_bounds__(256) void k3a_aq(const float* __restrict__ S,
                                              const float* __restrict__ sums,
                                              const float* __restrict__ sArr,
                                              const float* __restrict__ tArr,
                                              const float* __restrict__ qkv_w,
                                              const float* __restrict__ qkv_b,
                                              float* __restrict__ Aq) {
  const int ct = blockIdx.x, mt = blockIdx.y, b = blockIdx.z;
  const float* Sb = S + (size_t)b * kCP1 * kPS;
  const float HWf = (float)kHW;
  __shared__ float Wt[32][68];
  __shared__ float Gs[32][68];
  __shared__ float shs[kC], sht[kC], shx[kC], shr[kC];
  const int tid = threadIdx.x;
  {
    const float sv = sArr[b * kC + tid];
    const float tv = tArr[b * kC + tid];
    const float xv = sums[b * kC + tid];
    shs[tid] = sv; sht[tid] = tv; shx[tid] = xv;
    shr[tid] = sv * xv + tv * HWf;
  }
  __syncthreads();
  float acc[16];
#pragma unroll
  for (int i = 0; i < 16; ++i) acc[i] = 0.f;
  const int i0 = (tid & 15) * 4;   // m-local
  const int j0 = (tid >> 4) * 4;   // cp-local
  const int cp0 = ct * 64;

  for (int cb = 0; cb < kC; cb += 32) {
    int idx = tid;
#pragma unroll
    for (int r = 0; r < 2; ++r) {
      const int m = idx >> 3;
      const int c4 = (idx & 7) * 4;
      const int mg = mt * 64 + m;
      const int row = 12 * (mg >> 2) + (mg & 3);
      float4 v = *(const float4*)(qkv_w + (size_t)row * kC + cb + c4);
      Wt[c4 + 0][m] = v.x; Wt[c4 + 1][m] = v.y; Wt[c4 + 2][m] = v.z; Wt[c4 + 3][m] = v.w;
      idx += 256;
    }
    idx = tid;
#pragma unroll
    for (int r = 0; r < 2; ++r) {
      const int cc = idx >> 4;
      const int n4 = (idx & 15) * 4;
      const int rr = cb + cc;
      const float s_r = shs[rr], t_r = sht[rr], x_r = shx[rr];
      float4 o;
      if (cp0 + n4 < kC) {
        float4 v = *(const float4*)(Sb + (size_t)rr * kPS + cp0 + n4);
        const int cp = cp0 + n4;
        o.x = s_r * (shs[cp + 0] * v.x + sht[cp + 0] * x_r) + t_r * shr[cp + 0];
        o.y = s_r * (shs[cp + 1] * v.y + sht[cp + 1] * x_r) + t_r * shr[cp + 1];
        o.z = s_r * (shs[cp + 2] * v.z + sht[cp + 2] * x_r) + t_r * shr[cp + 2];
        o.w = s_r * (shs[cp + 3] * v.w + sht[cp + 3] * x_r) + t_r * shr[cp + 3];
      } else if (cp0 + n4 == kC) {      // augmented column 256
        o = (float4){s_r * x_r + t_r * HWf, 0.f, 0.f, 0.f};
      } else {
        o = (float4){0.f, 0.f, 0.f, 0.f};
      }
      *(float4*)&Gs[cc][n4] = o;
      idx += 256;
    }
    __syncthreads();
#pragma unroll
    for (int kk = 0; kk < 32; ++kk) {
      float4 a = *(const float4*)&Wt[kk][i0];
      float4 g = *(const float4*)&Gs[kk][j0];
      acc[0]  += a.x * g.x; acc[1]  += a.x * g.y; acc[2]  += a.x * g.z; acc[3]  += a.x * g.w;
      acc[4]  += a.y * g.x; acc[5]  += a.y * g.y; acc[6]  += a.y * g.z; acc[7]  += a.y * g.w;
      acc[8]  += a.z * g.x; acc[9]  += a.z * g.y; acc[10] += a.z * g.z; acc[11] += a.z * g.w;
      acc[12] += a.w * g.x; acc[13] += a.w * g.y; acc[14] += a.w * g.z; acc[15] += a.w * g.w;
    }
    __syncthreads();
  }
#pragma unroll
  for (int mi = 0; mi < 4; ++mi) {
    const int mg = mt * 64 + i0 + mi;
    const float bias = qkv_b[12 * (mg >> 2) + (mg & 3)];
#pragma unroll
    for (int cj = 0; cj < 4; ++cj) {
      const int cp = cp0 + j0 + cj;
      if (cp < kCP1) {
        const float g256 = (cp < kC) ? shr[cp] : HWf;   // Gram'[256][cp]
        Aq[((size_t)b * kC + mg) * kCP1 + cp] = acc[mi * 4 + cj] + bias * g256;
      }
    }
  }
}

// ---------------------------------------------------------------------------
// K3b: scores + softmax-over-heads fused. Block (de, b): all 64 heads' score
// for one (d,e) pair, then softmax across heads, writes P. grid (16, B).
// ---------------------------------------------------------------------------
__global__ __launch_bounds__(256) void k3b_sm(const float* __restrict__ Aq,
                                              const float* __restrict__ qkv_w,
                                              const float* __restrict__ qkv_b,
                                              float* __restrict__ P) {
  const int de = blockIdx.x, b = blockIdx.y;
  const int d = de >> 2, e = de & 3;
  __shared__ float sc[64];
  const int tid = threadIdx.x, wave = tid >> 6, lane = tid & 63;
  for (int hh = 0; hh < 16; ++hh) {
    const int h = wave * 16 + hh;
    const float* aqr = Aq + ((size_t)b * kC + h * 4 + d) * kCP1;
    const int krow = h * 12 + 4 + e;
    float s = 0.f;
#pragma unroll
    for (int it = 0; it < 4; ++it) {
      const int cp = lane + it * 64;
      s += aqr[cp] * qkv_w[(size_t)krow * kC + cp];
    }
    if (lane == 0) s += aqr[256] * qkv_b[krow];
#pragma unroll
    for (int off = 32; off; off >>= 1) s += __shfl_xor(s, off);
    if (lane == 0) sc[h] = 0.5f * s;
  }
  __syncthreads();
  if (tid < 64) {
    const float v = sc[tid];
    float m = v;
#pragma unroll
    for (int off = 32; off; off >>= 1) m = fmaxf(m, __shfl_xor(m, off));
    float ex = expf(v - m);
    float ssum = ex;
#pragma unroll
    for (int off = 32; off; off >>= 1) ssum += __shfl_xor(ssum, off);
    P[((size_t)(b * kHeads) + tid) * 16 + de] = ex / ssum;
  }
}

// ---------------------------------------------------------------------------
// K5a: M = P-mix of Wv' (row stride kPS). grid (256, B).
// ---------------------------------------------------------------------------
__global__ __launch_bounds__(256) void k5a_M(const float* __restrict__ P,
                                             const float* __restrict__ qkv_w,
                                             const float* __restrict__ qkv_b,
                                             float* __restrict__ M) {
  const int b = blockIdx.y;
  const int cidx = blockIdx.x;
  const int h = cidx >> 2, d = cidx & 3;
  const float p0 = P[((size_t)(b * kHeads) + h) * 16 + d * 4 + 0];
  const float p1 = P[((size_t)(b * kHeads) + h) * 16 + d * 4 + 1];
  const float p2 = P[((size_t)(b * kHeads) + h) * 16 + d * 4 + 2];
  const float p3 = P[((size_t)(b * kHeads) + h) * 16 + d * 4 + 3];
  for (int cp = threadIdx.x; cp < kCP1; cp += 256) {
    float a;
    if (cp < kC) {
      a = p0 * qkv_w[(size_t)(h * 12 + 8 + 0) * kC + cp] +
          p1 * qkv_w[(size_t)(h * 12 + 8 + 1) * kC + cp] +
          p2 * qkv_w[(size_t)(h * 12 + 8 + 2) * kC + cp] +
          p3 * qkv_w[(size_t)(h * 12 + 8 + 3) * kC + cp];
    } else {
      a = p0 * qkv_b[h * 12 + 8 + 0] + p1 * qkv_b[h * 12 + 8 + 1] +
          p2 * qkv_b[h * 12 + 8 + 2] + p3 * qkv_b[h * 12 + 8 + 3];
    }
    M[((size_t)b * kC + cidx) * kPS + cp] = a;
  }
}

// ---------------------------------------------------------------------------
// K5b: F = out_w @ M (tiled 64x64, K=256); emit G+I (fp16) + gvec partials
// per ct (no atomics). grid (5 cp-tiles, 4 o-tiles, B), 256 thr.
// ---------------------------------------------------------------------------
__global__ __launch_bounds__(256) void k5b_gemm(const float* __restrict__ M,
                                                const float* __restrict__ out_w,
                                                const float* __restrict__ sArr,
                                                const float* __restrict__ tArr,
                                                _Float16* __restrict__ GmH,
                                                float* __restrict__ gvP) {
  const int ct = blockIdx.x, ot = blockIdx.y, b = blockIdx.z;
  const float* Mb = M + (size_t)b * kC * kPS;
  __shared__ float Wt[32][68];
  __shared__ float Gs[32][68];
  __shared__ float gred[64][17];
  float acc[16];
#pragma unroll
  for (int i = 0; i < 16; ++i) acc[i] = 0.f;
  const int tid = threadIdx.x;
  const int i0 = (tid & 15) * 4;
  const int j0 = (tid >> 4) * 4;
  const int cp0 = ct * 64;

  for (int cb = 0; cb < kC; cb += 32) {
    int idx = tid;
#pragma unroll
    for (int r = 0; r < 2; ++r) {
      const int m = idx >> 3;
      const int c4 = (idx & 7) * 4;
      float4 v = *(const float4*)(out_w + (size_t)(ot * 64 + m) * kC + cb + c4);
      Wt[c4 + 0][m] = v.x; Wt[c4 + 1][m] = v.y; Wt[c4 + 2][m] = v.z; Wt[c4 + 3][m] = v.w;
      idx += 256;
    }
    idx = tid;
#pragma unroll
    for (int r = 0; r < 2; ++r) {
      const int cc = idx >> 4;
      const int n4 = (idx & 15) * 4;
      float4 v = {0.f, 0.f, 0.f, 0.f};
      if (cp0 + n4 < kCP1) v = *(const float4*)(Mb + (size_t)(cb + cc) * kPS + cp0 + n4);
      *(float4*)&Gs[cc][n4] = v;
      idx += 256;
    }
    __syncthreads();
#pragma unroll
    for (int kk = 0; kk < 32; ++kk) {
      float4 a = *(const float4*)&Wt[kk][i0];
      float4 g = *(const float4*)&Gs[kk][j0];
      acc[0]  += a.x * g.x; acc[1]  += a.x * g.y; acc[2]  += a.x * g.z; acc[3]  += a.x * g.w;
      acc[4]  += a.y * g.x; acc[5]  += a.y * g.y; acc[6]  += a.y * g.z; acc[7]  += a.y * g.w;
      acc[8]  += a.z * g.x; acc[9]  += a.z * g.y; acc[10] += a.z * g.z; acc[11] += a.z * g.w;
      acc[12] += a.w * g.x; acc[13] += a.w * g.y; acc[14] += a.w * g.z; acc[15] += a.w * g.w;
    }
    __syncthreads();
  }
  float gpart[4] = {0.f, 0.f, 0.f, 0.f};
#pragma unroll
  for (int mi = 0; mi < 4; ++mi) {
    const int o = ot * 64 + i0 + mi;
#pragma unroll
    for (int cj = 0; cj < 4; ++cj) {
      const int cp = cp0 + j0 + cj;
      const float f = acc[mi * 4 + cj];
      if (cp < kC) {
        // fold skip: G + I
        const float val = f * sArr[b * kC + cp] + ((cp == o) ? 1.0f : 0.0f);
        GmH[((size_t)b * kC + o) * kC + cp] = (_Float16)val;
        gpart[mi] += f * tArr[b * kC + cp];
      } else if (cp == kC) {
        gpart[mi] += f;
      }
    }
  }
#pragma unroll
  for (int mi = 0; mi < 4; ++mi) gred[i0 + mi][tid >> 4] = gpart[mi];
  __syncthreads();
  if (tid < 64) {
    float s = 0.f;
#pragma unroll
    for (int k = 0; k < 16; ++k) s += gred[tid][k];
    gvP[((size_t)b * kC + ot * 64 + tid) * 8 + ct] = s;   // per-ct partial
  }
}

// ---------------------------------------------------------------------------
// K6: out = (G+I) @ X + g via MFMA; coalesced LDS epilogue, no skip read.
// grid (HW/128, C/128, B), 256 thr.
// ---------------------------------------------------------------------------
__global__ __launch_bounds__(256) void k6_final(const _Float16* __restrict__ xT,
                                                const _Float16* __restrict__ GmH,
                                                const float* __restrict__ gvP,
                                                const float* __restrict__ out_b,
                                                float* __restrict__ out) {
  const int nt = blockIdx.x, ot = blockIdx.y, b = blockIdx.z;
  __shared__ __align__(16) char smem[64 * 132 * 4];   // 33792 B; aliased below
  __shared__ float gvs[128];
  _Float16* GT = (_Float16*)smem;                     // 16 KB
  _Float16* XT = (_Float16*)(smem + 16384);           // 16 KB
  float* Ep = (float*)smem;                           // epilogue 64 x 132 fp32
  const int tid = threadIdx.x;
  const int wave = tid >> 6, lane = tid & 63;
  const int wo = wave >> 1, wn = wave & 1;
  const int lrow = lane & 15, lgq = lane >> 4;

  if (tid < 128) {   // reduce gvec partials + bias once per block
    const int o = ot * 128 + tid;
    const float* gp = gvP + ((size_t)b * kC + o) * 8;
    gvs[tid] = gp[0] + gp[1] + gp[2] + gp[3] + gp[4] + out_b[o];
  }

  f32x4 acc[16];
#pragma unroll
  for (int i = 0; i < 16; ++i) acc[i] = (f32x4){0.f, 0.f, 0.f, 0.f};

  for (int cc = 0; cc < kC; cc += 64) {
#pragma unroll
    for (int rep = 0; rep < 4; ++rep) {
      const int gi = tid + rep * 256;
      const int r = gi >> 3, g = gi & 7;
      const size_t boff = (size_t)r * 128 + (((unsigned)(g ^ (r & 7))) << 4);
      uint4 gv = *(const uint4*)(GmH + ((size_t)(b * kC + ot * 128 + r)) * kC + cc + g * 8);
      *(uint4*)((char*)GT + boff) = gv;
      uint4 xv = *(const uint4*)(xT + ((size_t)b * kHW + nt * 128 + r) * kC + cc + g * 8);
      *(uint4*)((char*)XT + boff) = xv;
    }
    __syncthreads();
#pragma unroll
    for (int sub = 0; sub < 2; ++sub) {
      const int gq = sub * 4 + lgq;
      f16x8 afr[4], bfr[4];
#pragma unroll
      for (int ia = 0; ia < 4; ++ia) {
        const int r = wo * 64 + ia * 16 + lrow;
        afr[ia] = *(const f16x8*)((const char*)GT + (size_t)r * 128 + (((unsigned)(gq ^ (r & 7))) << 4));
      }
#pragma unroll
      for (int jb = 0; jb < 4; ++jb) {
        const int r = wn * 64 + jb * 16 + lrow;
        bfr[jb] = *(const f16x8*)((const char*)XT + (size_t)r * 128 + (((unsigned)(gq ^ (r & 7))) << 4));
      }
#pragma unroll
      for (int ia = 0; ia < 4; ++ia)
#pragma unroll
        for (int jb = 0; jb < 4; ++jb)
          acc[ia * 4 + jb] = __builtin_amdgcn_mfma_f32_16x16x32_f16(afr[ia], bfr[jb], acc[ia * 4 + jb], 0, 0, 0);
    }
    __syncthreads();
  }
  // Coalesced epilogue: two o-half passes through LDS.
#pragma unroll
  for (int p = 0; p < 2; ++p) {
    if (wo == p) {
#pragma unroll
      for (int ia = 0; ia < 4; ++ia)
#pragma unroll
        for (int jb = 0; jb < 4; ++jb)
#pragma unroll
          for (int reg = 0; reg < 4; ++reg)
            Ep[(size_t)(ia * 16 + lgq * 4 + reg) * 132 + wn * 64 + jb * 16 + lrow] =
                acc[ia * 4 + jb][reg];
    }
    __syncthreads();
#pragma unroll
    for (int it = 0; it < 8; ++it) {
      const int id = it * 256 + tid;
      const int row = id >> 5, nc = (id & 31) * 4;
      const int o = ot * 128 + p * 64 + row;
      const float gvv = gvs[p * 64 + row];
      float4 e = *(const float4*)&Ep[(size_t)row * 132 + nc];
      const size_t gidx = ((size_t)b * kC + o) * kHW + nt * 128 + nc;
      float4 res = {e.x + gvv, e.y + gvv, e.z + gvv, e.w + gvv};
      *(float4*)&out[gidx] = res;
    }
    __syncthreads();
  }
}

extern "C" void kernel_launch(void* const* d_in, const int* in_sizes, int n_in,
                              void* d_out, int out_size, void* d_ws, size_t ws_size,
                              hipStream_t stream) {
  const float* x    = (const float*)d_in[0];
  const float* gnw  = (const float*)d_in[1];
  const float* gnb  = (const float*)d_in[2];
  const float* qkvw = (const float*)d_in[3];
  const float* qkvb = (const float*)d_in[4];
  const float* outw = (const float*)d_in[5];
  const float* outb = (const float*)d_in[6];
  float* out = (float*)d_out;
  float* ws = (float*)d_ws;

  _Float16* xT   = (_Float16*)(ws + oXT);
  _Float16* xH   = (_Float16*)(ws + oXH);
  float* Spart   = ws + oSpart;
  float* S       = ws + oS;
  float* sumsP   = ws + oSumsP;
  float* sums    = ws + oSums;
  float* gvP     = ws + oGvP;
  float* sArr    = ws + oSc;
  float* tArr    = ws + oTc;
  float* P       = ws + oP;
  float* Aq      = ws + oAq;
  float* M       = ws + oM;
  _Float16* GmH  = (_Float16*)(ws + oGmH);

  k0_tr<<<dim3(kHW / 64, kC / 64, kB), 256, 0, stream>>>(x, xT, xH, sumsP);
  k1_syrk<<<dim3(3 * kNSplit, kB), 256, 0, stream>>>(xH, Spart);
  k1r_reduce<<<dim3(3 * kB * 16), 256, 0, stream>>>(Spart, S);
  k2a_stats<<<kB, 256, 0, stream>>>(S, sumsP, gnw, gnb, sArr, tArr, sums);
  k3a_aq<<<dim3(5, 4, kB), 256, 0, stream>>>(S, sums, sArr, tArr, qkvw, qkvb, Aq);
  k3b_sm<<<dim3(16, kB), 256, 0, stream>>>(Aq, qkvw, qkvb, P);
  k5a_M<<<dim3(kC, kB), 256, 0, stream>>>(P, qkvw, qkvb, M);
  k5b_gemm<<<dim3(5, 4, kB), 256, 0, stream>>>(M, outw, sArr, tArr, GmH, gvP);
  k6_final<<<dim3(kHW / 128, kC / 128, kB), 256, 0, stream>>>(xT, GmH, gvP, outb, out);
}